// Round 4
// baseline (251.605 us; speedup 1.0000x reference)
//
#include <hip/hip_runtime.h>
#include <hip/hip_bf16.h>
#include <stdint.h>

// ---------------------------------------------------------------------------
// MaskedAttention: out = colsoftmax(tril(Q K^T / sqrt(E))) @ V
// B=4, T=2048, E=H=1024.  Softmax over the QUERY axis (axis=1) per column j.
//
// R14 (R11-R13 8-phase QKV all FAILED with deterministic absmax ~2.2,
// independent of swizzle and vmcnt variants -> shelved; QKV reverted to the
// R10-verified MODE 4).  New change this round, on the passing structure:
//  * MODE 5 (scores) epilogue: was 64 scalar 2B global stores/thread at
//    row-stride 2048 (~25% burst efficiency on a 32 MB write).  Now: exp'd
//    bf16 acc -> 128x128 LDS tile (sA/sB made contiguous, same 32 KB, dead
//    after main loop) -> 8 passes x 256 thr x 16B fully-coalesced stores
//    (256B bursts per 16-lane group).  Column partials unchanged.
//  * side effect: scores/PV dispatches should now appear in top-5 counters.
//
// Workspace 80 MB, liveness overlays:
//   [ 0,16) Xb      (dead after QKV)      -> E bf16 [0,32) at scores step
//   [16,22) WqT|WkT|WvT contiguous [3072,1024] (dead after QKV)
//   [32,48) Qb      (dead after scores)   -> Linv (32 KB) after scores
//   [48,64) Kb      (dead after scores)
//   [64,80) Vt [B,H,T] (written by QKV epilogue, scaled in place, read by PV)
//   partial column sums [B,32,T] fp32 (1 MB) live in d_out (dead until PV).
// ---------------------------------------------------------------------------

typedef short bf16x8 __attribute__((ext_vector_type(8)));
typedef float f32x4  __attribute__((ext_vector_type(4)));

__device__ __forceinline__ unsigned short f2bf(float f) {
    union { float f; unsigned u; } x; x.f = f;
    unsigned r = x.u + 0x7FFFu + ((x.u >> 16) & 1u);
    return (unsigned short)(r >> 16);
}
__device__ __forceinline__ float bf2f(unsigned short h) {
    union { unsigned u; float f; } x; x.u = ((unsigned)h) << 16;
    return x.f;
}

// ---------------------------------------------------------------------------
__global__ __launch_bounds__(256) void cast_kernel(
    const float* __restrict__ in, unsigned short* __restrict__ out, size_t n)
{
    size_t i = ((size_t)blockIdx.x * 256 + threadIdx.x) * 4;
    if (i >= n) return;
    float4 v = *(const float4*)(in + i);
    union { unsigned short h[4]; unsigned long long u; } p;
    p.h[0] = f2bf(v.x); p.h[1] = f2bf(v.y); p.h[2] = f2bf(v.z); p.h[3] = f2bf(v.w);
    *(unsigned long long*)(out + i) = p.u;
}

// transpose + cast: W [R,C] fp32 -> Wt [C,R] bf16. 64x64 tile, 256 threads.
__global__ __launch_bounds__(256) void transpose_cast_kernel(
    const float* __restrict__ in, unsigned short* __restrict__ out, int R, int C)
{
    __shared__ unsigned short tile[64][65];
    int tx = threadIdx.x & 63, ty = threadIdx.x >> 6;
    int r0 = blockIdx.y * 64, c0 = blockIdx.x * 64;
#pragma unroll
    for (int i = 0; i < 16; ++i) {
        int r = ty + i * 4;
        tile[r][tx] = f2bf(in[(size_t)(r0 + r) * C + c0 + tx]);
    }
    __syncthreads();
#pragma unroll
    for (int i = 0; i < 16; ++i) {
        int c = ty + i * 4;
        out[(size_t)(c0 + c) * R + r0 + tx] = tile[tx][c];
    }
}

// ---------------------------------------------------------------------------
// NT bf16 GEMM: C[M,N] = A[M,K] * B[N,K]^T
// 128x128 tile, BK=64, 256 threads = 4 waves of 64x64, 16x16x32 bf16 MFMA,
// XOR-swizzled LDS, register-prefetch pipeline (named scalars).
// MODE 2: C fp32, K limited to m0+128   (PV; E causally zero-filled);
//         natural grid (8,16,B) -> xcd = tn band.
// MODE 4: fused QKV; XCD-banded swizzle (8 tm-rows per XCD).
// MODE 5: scores: 1D triangular grid (136,1,B); E = exp(s*scale) bf16 via
//         LDS-coalesced store (masked on diagonal tile) + column partials
//         -> fpar[b][rh][j]
// ---------------------------------------------------------------------------
template <int MODE>
__global__ __launch_bounds__(256, 3) void gemm_nt(
    const unsigned short* __restrict__ A, const unsigned short* __restrict__ B,
    void* __restrict__ Cout, unsigned short* __restrict__ C2,
    unsigned short* __restrict__ C3, float* __restrict__ fpar,
    int M, int N, int K,
    size_t sAb, size_t sBb, size_t sCb, float scale, int ldt)
{
    int tn, tm, bz = blockIdx.z;
    if (MODE == 4) {
        // XCD-banded: xcd = id&7 owns tm in [xcd*8, xcd*8+8) x all 24 tn
        unsigned id = blockIdx.y * gridDim.x + blockIdx.x;
        unsigned xcd = id & 7, k2 = id >> 3;
        tm = (int)(xcd * 8 + (k2 & 7));
        tn = (int)(k2 >> 3);
    } else if (MODE == 5) {
        // 1D triangular decode: tid -> (tm, tn<=tm)
        int tid = blockIdx.x;
        tm = (int)((sqrtf(8.f * (float)tid + 1.f) - 1.f) * 0.5f);
        while ((tm + 1) * (tm + 2) / 2 <= tid) ++tm;
        while (tm * (tm + 1) / 2 > tid) --tm;
        tn = tid - tm * (tm + 1) / 2;
    } else {
        tn = blockIdx.x; tm = blockIdx.y;
    }
    A += (size_t)bz * sAb;
    B += (size_t)bz * sBb;
    int m0 = tm * 128, n0 = tn * 128;
    int kmax = (MODE == 2) ? (m0 + 128) : K;

    // contiguous 32 KB: A-tile at [0,16K), B-tile at [16K,32K); reused as a
    // 128x128 bf16 tile by the MODE-5 epilogue.
    __shared__ unsigned short sAB[2 * 128 * 64];
    char* sAc = (char*)sAB;
    char* sBc = (char*)sAB + 16384;

    unsigned t = threadIdx.x, lane = t & 63, wave = t >> 6;

    // staging: chunk ca = t + 256q, row = (ca&511)>>2, LDS byte ca*16.
    // Swizzle: global 16B group g = (ca&3) ^ ((row>>1)&3).
    unsigned srow = t >> 2;
    unsigned gsw = (t & 3) ^ ((t >> 3) & 3);
    const unsigned short* pA = A + (size_t)(m0 + srow) * K + gsw * 8;
    const unsigned short* pB = B + (size_t)(n0 + srow) * K + gsw * 8;
    const size_t rstep = (size_t)64 * K;
    unsigned ldsOff = t * 16;   // bytes; chunks q1/q2/q3 at +4096/+8192/+12288

    unsigned wm = (wave >> 1) * 64, wn = (wave & 1) * 64;
    unsigned lrow = lane & 15;
    // swizzled k-offset, lane-constant (row bits 1..2 == lrow bits 1..2)
    unsigned lk = ((lane >> 4) ^ ((lane >> 1) & 3)) * 8;
    const short* sAs = (const short*)sAB;
    const short* sBs = (const short*)(sAB + 128 * 64);

    f32x4 acc[4][4] = {};

    // prologue: prefetch tile 0 into named registers
    int4 rA0 = *(const int4*)(pA);
    int4 rA1 = *(const int4*)(pA + rstep);
    int4 rA2 = *(const int4*)(pA + 32);
    int4 rA3 = *(const int4*)(pA + rstep + 32);
    int4 rB0 = *(const int4*)(pB);
    int4 rB1 = *(const int4*)(pB + rstep);
    int4 rB2 = *(const int4*)(pB + 32);
    int4 rB3 = *(const int4*)(pB + rstep + 32);

    for (int k0 = 0; k0 < kmax; k0 += 64) {
        __syncthreads();                 // prev LDS reads done; vmcnt drained
        *(int4*)(sAc + ldsOff)         = rA0;
        *(int4*)(sAc + ldsOff + 4096)  = rA1;
        *(int4*)(sAc + ldsOff + 8192)  = rA2;
        *(int4*)(sAc + ldsOff + 12288) = rA3;
        *(int4*)(sBc + ldsOff)         = rB0;
        *(int4*)(sBc + ldsOff + 4096)  = rB1;
        *(int4*)(sBc + ldsOff + 8192)  = rB2;
        *(int4*)(sBc + ldsOff + 12288) = rB3;
        __syncthreads();                 // publish LDS tile

        if (k0 + 64 < kmax) {            // issue next tile; lands during MFMA
            pA += 64; pB += 64;
            rA0 = *(const int4*)(pA);
            rA1 = *(const int4*)(pA + rstep);
            rA2 = *(const int4*)(pA + 32);
            rA3 = *(const int4*)(pA + rstep + 32);
            rB0 = *(const int4*)(pB);
            rB1 = *(const int4*)(pB + rstep);
            rB2 = *(const int4*)(pB + 32);
            rB3 = *(const int4*)(pB + rstep + 32);
        }

#pragma unroll
        for (int kk = 0; kk < 2; ++kk) {
            bf16x8 a[4], b[4];
#pragma unroll
            for (int i = 0; i < 4; ++i) {
                a[i] = *(const bf16x8*)(sAs + kk * 4096 + (wm + i * 16 + lrow) * 32 + lk);
                b[i] = *(const bf16x8*)(sBs + kk * 4096 + (wn + i * 16 + lrow) * 32 + lk);
            }
#pragma unroll
            for (int i = 0; i < 4; ++i)
#pragma unroll
                for (int j = 0; j < 4; ++j)
                    acc[i][j] = __builtin_amdgcn_mfma_f32_16x16x32_bf16(
                        a[i], b[j], acc[i][j], 0, 0, 0);
        }
    }

    // epilogue: D col = lane&15, row = (lane>>4)*4 + reg
    unsigned col = lane & 15, rq = (lane >> 4) * 4;
    if (MODE == 2) {
        float* C = (float*)Cout + (size_t)bz * sCb;
#pragma unroll
        for (int i = 0; i < 4; ++i)
#pragma unroll
            for (int j = 0; j < 4; ++j)
#pragma unroll
                for (int r = 0; r < 4; ++r)
                    C[(size_t)(m0 + wm + i * 16 + rq + r) * N + n0 + wn + j * 16 + col] =
                        acc[i][j][r];
    } else if (MODE == 5) {   // scores -> E = exp, LDS-coalesced + col partials
        unsigned short* Ebp = (unsigned short*)Cout + (size_t)bz * sCb;
        float* par = fpar + (size_t)bz * 32 * 2048;
        bool diag = (tm == tn);
        unsigned short* tile = sAB;          // 128x128 bf16 = 32 KB
        __syncthreads();                     // all waves done reading A/B tiles
#pragma unroll
        for (int jj = 0; jj < 4; ++jj) {
            float csum = 0.f;
            int jl = (int)(wn + jj * 16 + col);
            int jg = n0 + jl;
#pragma unroll
            for (int ii = 0; ii < 4; ++ii) {
#pragma unroll
                for (int r = 0; r < 4; ++r) {
                    int il = (int)(wm + ii * 16 + rq + r);
                    int ig = m0 + il;
                    unsigned short us = 0;
                    if (!diag || ig >= jg)
                        us = f2bf(__expf(acc[ii][jj][r] * scale));
                    tile[il * 128 + jl] = us;
                    csum += bf2f(us);
                }
            }
            csum += __shfl_xor(csum, 16);
            csum += __shfl_xor(csum, 32);
            if (lane < 16) {
                int rh = (m0 + wm) >> 6;
                par[(size_t)rh * 2048 + n0 + wn + jj * 16 + lane] = csum;
            }
        }
        __syncthreads();                     // tile fully written
        // coalesced store: 8 passes x 256 threads x 16B (256B/16-lane group)
        {
            unsigned rr = t >> 4, cc = (t & 15) * 8;
#pragma unroll
            for (int p = 0; p < 8; ++p) {
                int li = (int)(p * 16 + rr);
                int4 v = *(const int4*)(tile + li * 128 + cc);
                *(int4*)(Ebp + (size_t)(m0 + li) * N + n0 + cc) = v;
            }
        }
    } else {                  // MODE 4: fused QKV
        if (n0 < 2048) {      // Q or K, row-major [8192,1024]
            unsigned short* C = (n0 < 1024) ? (unsigned short*)Cout : C2;
            int nb = n0 & 1023;
#pragma unroll
            for (int i = 0; i < 4; ++i)
#pragma unroll
                for (int j = 0; j < 4; ++j)
#pragma unroll
                    for (int r = 0; r < 4; ++r)
                        C[(size_t)(m0 + wm + i * 16 + rq + r) * 1024 + nb + wn + j * 16 + col] =
                            f2bf(acc[i][j][r]);
        } else {              // V transposed into Vt [B,H,T]
            int batch = m0 >> 11, tb = m0 & 2047;
            unsigned short* C = C3 + (size_t)batch * 1024 * 2048;
#pragma unroll
            for (int i = 0; i < 4; ++i)
#pragma unroll
                for (int j = 0; j < 4; ++j) {
                    union { unsigned short h[4]; unsigned long long u; } p;
#pragma unroll
                    for (int r = 0; r < 4; ++r) p.h[r] = f2bf(acc[i][j][r]);
                    int h = (n0 - 2048) + wn + j * 16 + col;
                    int t0 = tb + wm + i * 16 + rq;
                    *(unsigned long long*)(C + (size_t)h * ldt + t0) = p.u;
                }
        }
    }
}

// ---------------------------------------------------------------------------
// Linv[b][j] = 1 / sum_rh partial[b][rh][j], rh from j>>6 (lower rows only).
// ---------------------------------------------------------------------------
__global__ __launch_bounds__(256) void colsum_inv(
    const float* __restrict__ par, float* __restrict__ Linv, int T)
{
    int b = blockIdx.y;
    int j = blockIdx.x * 256 + threadIdx.x;
    const float* p = par + (size_t)b * 32 * 2048;
    float s = 0.f;
    for (int rh = j >> 6; rh < 32; ++rh) s += p[(size_t)rh * 2048 + j];
    Linv[b * 2048 + j] = 1.0f / s;
}

// ---------------------------------------------------------------------------
// Vt[b][h][t] *= Linv[b][t]   (Vt [B,H,T] bf16, 8 elems/thread)
// ---------------------------------------------------------------------------
__global__ __launch_bounds__(256) void scale_v(
    unsigned short* __restrict__ Vt, const float* __restrict__ Linv)
{
    size_t idx = ((size_t)blockIdx.x * 256 + threadIdx.x) * 8;
    int b = (int)(idx >> 21);            // H*T = 2^21
    int tt = (int)(idx & 2047);
    bf16x8 v = *(bf16x8*)(Vt + idx);
    const float* L = Linv + b * 2048 + tt;
#pragma unroll
    for (int e = 0; e < 8; ++e)
        v[e] = (short)f2bf(bf2f((unsigned short)v[e]) * L[e]);
    *(bf16x8*)(Vt + idx) = v;
}

// ---------------------------------------------------------------------------
extern "C" void kernel_launch(void* const* d_in, const int* in_sizes, int n_in,
                              void* d_out, int out_size, void* d_ws, size_t ws_size,
                              hipStream_t stream)
{
    const int B = 4, T = 2048, E = 1024, H = 1024;
    const int M = B * T;                       // 8192
    const float* X  = (const float*)d_in[0];
    const float* Wq = (const float*)d_in[1];
    const float* Wk = (const float*)d_in[2];
    const float* Wv = (const float*)d_in[3];
    float* out = (float*)d_out;
    char* ws = (char*)d_ws;
    const size_t MB = 1024 * 1024;

    unsigned short* Xb  = (unsigned short*)(ws + 0);        // [ 0,16) MB
    unsigned short* WqT = (unsigned short*)(ws + 16 * MB);  // [16,18) contiguous with WkT,WvT
    unsigned short* WkT = (unsigned short*)(ws + 18 * MB);  // [18,20)
    unsigned short* WvT = (unsigned short*)(ws + 20 * MB);  // [20,22)
    unsigned short* Qb  = (unsigned short*)(ws + 32 * MB);  // [32,48)
    unsigned short* Kb  = (unsigned short*)(ws + 48 * MB);  // [48,64)
    unsigned short* Vt  = (unsigned short*)(ws + 64 * MB);  // [64,80) Vt [B,H,T]
    unsigned short* Eb  = (unsigned short*)(ws + 0);        // [ 0,32) overlays Xb/W (dead)
    float*          Linv = (float*)(ws + 32 * MB);          // 32 KB over dead Qb
    float*          par  = (float*)d_out;                   // 1 MB, dead until PV

    // 1. casts / weight transposes
    cast_kernel<<<dim3((M * E) / 1024), 256, 0, stream>>>(X, Xb, (size_t)M * E);
    transpose_cast_kernel<<<dim3(H / 64, E / 64), 256, 0, stream>>>(Wq, WqT, E, H);
    transpose_cast_kernel<<<dim3(H / 64, E / 64), 256, 0, stream>>>(Wk, WkT, E, H);
    transpose_cast_kernel<<<dim3(H / 64, E / 64), 256, 0, stream>>>(Wv, WvT, E, H);

    // 2. fused QKV: [8192,3072] vs concat W^T; Q,K row-major, V -> Vt [B,H,T]
    gemm_nt<4><<<dim3(3 * H / 128, M / 128, 1), 256, 0, stream>>>(
        Xb, WqT, Qb, Kb, Vt, nullptr, M, 3 * H, E, 0, 0, 0, 1.f, T);

    // 3. scores: E[i][j] = exp((Q K^T)[i][j]/32) masked, + column partials
    //    1D triangular grid: 136 lower-triangle tiles per batch
    gemm_nt<5><<<dim3(136, 1, B), 256, 0, stream>>>(
        Qb, Kb, Eb, nullptr, nullptr, par, T, T, H,
        (size_t)T * H, (size_t)T * H, (size_t)T * T, 0.03125f, T);

    // 4. Linv = 1/colsum;  Vt *= Linv (folds softmax denominator into V)
    colsum_inv<<<dim3(T / 256, B), 256, 0, stream>>>(par, Linv, T);
    scale_v<<<dim3((B * H * T) / 2048), 256, 0, stream>>>(Vt, Linv);

    // 5. out = E (V/L)  (NT with scaled Vt), causal K-limit
    gemm_nt<2><<<dim3(H / 128, T / 128, B), 256, 0, stream>>>(
        Eb, Vt, out, nullptr, nullptr, nullptr, T, H, T,
        (size_t)T * T, (size_t)H * T, (size_t)T * H, 1.f, 0);
}

// Round 5
// 248.274 us; speedup vs baseline: 1.0134x; 1.0134x over previous
//
#include <hip/hip_runtime.h>
#include <hip/hip_bf16.h>
#include <stdint.h>

// ---------------------------------------------------------------------------
// MaskedAttention: out = colsoftmax(tril(Q K^T / sqrt(E))) @ V
// B=4, T=2048, E=H=1024.  Softmax over the QUERY axis (axis=1) per column j.
//
// R15 (R14 passed 251.6us; LDS-coalesced E-store neutral -> scores not
// store-bound.  All top-5 counter rows are STILL QKV: scores/PV (~165us
// combined, ~220 TF) have never been profiled.  Mapping-only round):
//  * QKV split into two 768-block dispatches (tm 0-31 / 32-63; one full
//    occupancy round each, ~31.7us) -> scores & PV enter top-5 counters.
//    XCD banding preserved: 4 tm-rows x 24 tn per XCD, offset via sCb.
//  * scores: XCD-chunked triangular mapping (tile = (bx&7)*17 + bx>>3,
//    bijective since 136 = 8x17): each XCD owns 17 contiguous tri-tiles
//    per batch -> Q/K panel reuse in its L2 (~3-4.5 MB working set) vs
//    previous all-XCD scatter (every XCD fetched every panel).
//
// Workspace 80 MB, liveness overlays:
//   [ 0,16) Xb      (dead after QKV)      -> E bf16 [0,32) at scores step
//   [16,22) WqT|WkT|WvT contiguous [3072,1024] (dead after QKV)
//   [32,48) Qb      (dead after scores)   -> Linv (32 KB) after scores
//   [48,64) Kb      (dead after scores)
//   [64,80) Vt [B,H,T] (written by QKV epilogue, scaled in place, read by PV)
//   partial column sums [B,32,T] fp32 (1 MB) live in d_out (dead until PV).
// ---------------------------------------------------------------------------

typedef short bf16x8 __attribute__((ext_vector_type(8)));
typedef float f32x4  __attribute__((ext_vector_type(4)));

__device__ __forceinline__ unsigned short f2bf(float f) {
    union { float f; unsigned u; } x; x.f = f;
    unsigned r = x.u + 0x7FFFu + ((x.u >> 16) & 1u);
    return (unsigned short)(r >> 16);
}
__device__ __forceinline__ float bf2f(unsigned short h) {
    union { unsigned u; float f; } x; x.u = ((unsigned)h) << 16;
    return x.f;
}

// ---------------------------------------------------------------------------
__global__ __launch_bounds__(256) void cast_kernel(
    const float* __restrict__ in, unsigned short* __restrict__ out, size_t n)
{
    size_t i = ((size_t)blockIdx.x * 256 + threadIdx.x) * 4;
    if (i >= n) return;
    float4 v = *(const float4*)(in + i);
    union { unsigned short h[4]; unsigned long long u; } p;
    p.h[0] = f2bf(v.x); p.h[1] = f2bf(v.y); p.h[2] = f2bf(v.z); p.h[3] = f2bf(v.w);
    *(unsigned long long*)(out + i) = p.u;
}

// transpose + cast: W [R,C] fp32 -> Wt [C,R] bf16. 64x64 tile, 256 threads.
__global__ __launch_bounds__(256) void transpose_cast_kernel(
    const float* __restrict__ in, unsigned short* __restrict__ out, int R, int C)
{
    __shared__ unsigned short tile[64][65];
    int tx = threadIdx.x & 63, ty = threadIdx.x >> 6;
    int r0 = blockIdx.y * 64, c0 = blockIdx.x * 64;
#pragma unroll
    for (int i = 0; i < 16; ++i) {
        int r = ty + i * 4;
        tile[r][tx] = f2bf(in[(size_t)(r0 + r) * C + c0 + tx]);
    }
    __syncthreads();
#pragma unroll
    for (int i = 0; i < 16; ++i) {
        int c = ty + i * 4;
        out[(size_t)(c0 + c) * R + r0 + tx] = tile[tx][c];
    }
}

// ---------------------------------------------------------------------------
// NT bf16 GEMM: C[M,N] = A[M,K] * B[N,K]^T
// 128x128 tile, BK=64, 256 threads = 4 waves of 64x64, 16x16x32 bf16 MFMA,
// XOR-swizzled LDS, register-prefetch pipeline (named scalars).
// MODE 2: C fp32, K limited to m0+128   (PV; E causally zero-filled);
//         natural grid (8,16,B) -> xcd = tn band.
// MODE 4: fused QKV; XCD-banded (4 tm-rows x 24 tn per XCD), tm offset in sCb;
//         launched twice (tm 0-31, 32-63), 768 blocks each.
// MODE 5: scores: XCD-chunked triangular grid (136,1,B); E = exp(s*scale)
//         bf16 via LDS-coalesced store (masked on diagonal tile) + column
//         partials -> fpar[b][rh][j]
// ---------------------------------------------------------------------------
template <int MODE>
__global__ __launch_bounds__(256, 3) void gemm_nt(
    const unsigned short* __restrict__ A, const unsigned short* __restrict__ B,
    void* __restrict__ Cout, unsigned short* __restrict__ C2,
    unsigned short* __restrict__ C3, float* __restrict__ fpar,
    int M, int N, int K,
    size_t sAb, size_t sBb, size_t sCb, float scale, int ldt)
{
    int tn, tm, bz = blockIdx.z;
    if (MODE == 4) {
        // XCD-banded: xcd = id&7 owns tm in [xcd*4, xcd*4+4) x all 24 tn;
        // dispatch tm-offset passed in sCb (0 or 32).
        unsigned id = blockIdx.y * gridDim.x + blockIdx.x;   // [0,768)
        unsigned xcd = id & 7, k2 = id >> 3;                 // k2 in [0,96)
        tm = (int)(xcd * 4 + (k2 & 3)) + (int)sCb;
        tn = (int)(k2 >> 2);
    } else if (MODE == 5) {
        // XCD-chunked triangular: tile = (bx&7)*17 + bx>>3 (136 = 8x17),
        // then 1D triangular decode tile -> (tm, tn<=tm)
        int bxr = blockIdx.x;
        int tid = (bxr & 7) * 17 + (bxr >> 3);
        tm = (int)((sqrtf(8.f * (float)tid + 1.f) - 1.f) * 0.5f);
        while ((tm + 1) * (tm + 2) / 2 <= tid) ++tm;
        while (tm * (tm + 1) / 2 > tid) --tm;
        tn = tid - tm * (tm + 1) / 2;
    } else {
        tn = blockIdx.x; tm = blockIdx.y;
    }
    A += (size_t)bz * sAb;
    B += (size_t)bz * sBb;
    int m0 = tm * 128, n0 = tn * 128;
    int kmax = (MODE == 2) ? (m0 + 128) : K;

    // contiguous 32 KB: A-tile at [0,16K), B-tile at [16K,32K); reused as a
    // 128x128 bf16 tile by the MODE-5 epilogue.
    __shared__ unsigned short sAB[2 * 128 * 64];
    char* sAc = (char*)sAB;
    char* sBc = (char*)sAB + 16384;

    unsigned t = threadIdx.x, lane = t & 63, wave = t >> 6;

    // staging: chunk ca = t + 256q, row = (ca&511)>>2, LDS byte ca*16.
    // Swizzle: global 16B group g = (ca&3) ^ ((row>>1)&3).
    unsigned srow = t >> 2;
    unsigned gsw = (t & 3) ^ ((t >> 3) & 3);
    const unsigned short* pA = A + (size_t)(m0 + srow) * K + gsw * 8;
    const unsigned short* pB = B + (size_t)(n0 + srow) * K + gsw * 8;
    const size_t rstep = (size_t)64 * K;
    unsigned ldsOff = t * 16;   // bytes; chunks q1/q2/q3 at +4096/+8192/+12288

    unsigned wm = (wave >> 1) * 64, wn = (wave & 1) * 64;
    unsigned lrow = lane & 15;
    // swizzled k-offset, lane-constant (row bits 1..2 == lrow bits 1..2)
    unsigned lk = ((lane >> 4) ^ ((lane >> 1) & 3)) * 8;
    const short* sAs = (const short*)sAB;
    const short* sBs = (const short*)(sAB + 128 * 64);

    f32x4 acc[4][4] = {};

    // prologue: prefetch tile 0 into named registers
    int4 rA0 = *(const int4*)(pA);
    int4 rA1 = *(const int4*)(pA + rstep);
    int4 rA2 = *(const int4*)(pA + 32);
    int4 rA3 = *(const int4*)(pA + rstep + 32);
    int4 rB0 = *(const int4*)(pB);
    int4 rB1 = *(const int4*)(pB + rstep);
    int4 rB2 = *(const int4*)(pB + 32);
    int4 rB3 = *(const int4*)(pB + rstep + 32);

    for (int k0 = 0; k0 < kmax; k0 += 64) {
        __syncthreads();                 // prev LDS reads done; vmcnt drained
        *(int4*)(sAc + ldsOff)         = rA0;
        *(int4*)(sAc + ldsOff + 4096)  = rA1;
        *(int4*)(sAc + ldsOff + 8192)  = rA2;
        *(int4*)(sAc + ldsOff + 12288) = rA3;
        *(int4*)(sBc + ldsOff)         = rB0;
        *(int4*)(sBc + ldsOff + 4096)  = rB1;
        *(int4*)(sBc + ldsOff + 8192)  = rB2;
        *(int4*)(sBc + ldsOff + 12288) = rB3;
        __syncthreads();                 // publish LDS tile

        if (k0 + 64 < kmax) {            // issue next tile; lands during MFMA
            pA += 64; pB += 64;
            rA0 = *(const int4*)(pA);
            rA1 = *(const int4*)(pA + rstep);
            rA2 = *(const int4*)(pA + 32);
            rA3 = *(const int4*)(pA + rstep + 32);
            rB0 = *(const int4*)(pB);
            rB1 = *(const int4*)(pB + rstep);
            rB2 = *(const int4*)(pB + 32);
            rB3 = *(const int4*)(pB + rstep + 32);
        }

#pragma unroll
        for (int kk = 0; kk < 2; ++kk) {
            bf16x8 a[4], b[4];
#pragma unroll
            for (int i = 0; i < 4; ++i) {
                a[i] = *(const bf16x8*)(sAs + kk * 4096 + (wm + i * 16 + lrow) * 32 + lk);
                b[i] = *(const bf16x8*)(sBs + kk * 4096 + (wn + i * 16 + lrow) * 32 + lk);
            }
#pragma unroll
            for (int i = 0; i < 4; ++i)
#pragma unroll
                for (int j = 0; j < 4; ++j)
                    acc[i][j] = __builtin_amdgcn_mfma_f32_16x16x32_bf16(
                        a[i], b[j], acc[i][j], 0, 0, 0);
        }
    }

    // epilogue: D col = lane&15, row = (lane>>4)*4 + reg
    unsigned col = lane & 15, rq = (lane >> 4) * 4;
    if (MODE == 2) {
        float* C = (float*)Cout + (size_t)bz * sCb;
#pragma unroll
        for (int i = 0; i < 4; ++i)
#pragma unroll
            for (int j = 0; j < 4; ++j)
#pragma unroll
                for (int r = 0; r < 4; ++r)
                    C[(size_t)(m0 + wm + i * 16 + rq + r) * N + n0 + wn + j * 16 + col] =
                        acc[i][j][r];
    } else if (MODE == 5) {   // scores -> E = exp, LDS-coalesced + col partials
        unsigned short* Ebp = (unsigned short*)Cout + (size_t)bz * sCb;
        float* par = fpar + (size_t)bz * 32 * 2048;
        bool diag = (tm == tn);
        unsigned short* tile = sAB;          // 128x128 bf16 = 32 KB
        __syncthreads();                     // all waves done reading A/B tiles
#pragma unroll
        for (int jj = 0; jj < 4; ++jj) {
            float csum = 0.f;
            int jl = (int)(wn + jj * 16 + col);
            int jg = n0 + jl;
#pragma unroll
            for (int ii = 0; ii < 4; ++ii) {
#pragma unroll
                for (int r = 0; r < 4; ++r) {
                    int il = (int)(wm + ii * 16 + rq + r);
                    int ig = m0 + il;
                    unsigned short us = 0;
                    if (!diag || ig >= jg)
                        us = f2bf(__expf(acc[ii][jj][r] * scale));
                    tile[il * 128 + jl] = us;
                    csum += bf2f(us);
                }
            }
            csum += __shfl_xor(csum, 16);
            csum += __shfl_xor(csum, 32);
            if (lane < 16) {
                int rh = (m0 + wm) >> 6;
                par[(size_t)rh * 2048 + n0 + wn + jj * 16 + lane] = csum;
            }
        }
        __syncthreads();                     // tile fully written
        // coalesced store: 8 passes x 256 threads x 16B (256B/16-lane group)
        {
            unsigned rr = t >> 4, cc = (t & 15) * 8;
#pragma unroll
            for (int p = 0; p < 8; ++p) {
                int li = (int)(p * 16 + rr);
                int4 v = *(const int4*)(tile + li * 128 + cc);
                *(int4*)(Ebp + (size_t)(m0 + li) * N + n0 + cc) = v;
            }
        }
    } else {                  // MODE 4: fused QKV
        if (n0 < 2048) {      // Q or K, row-major [8192,1024]
            unsigned short* C = (n0 < 1024) ? (unsigned short*)Cout : C2;
            int nb = n0 & 1023;
#pragma unroll
            for (int i = 0; i < 4; ++i)
#pragma unroll
                for (int j = 0; j < 4; ++j)
#pragma unroll
                    for (int r = 0; r < 4; ++r)
                        C[(size_t)(m0 + wm + i * 16 + rq + r) * 1024 + nb + wn + j * 16 + col] =
                            f2bf(acc[i][j][r]);
        } else {              // V transposed into Vt [B,H,T]
            int batch = m0 >> 11, tb = m0 & 2047;
            unsigned short* C = C3 + (size_t)batch * 1024 * 2048;
#pragma unroll
            for (int i = 0; i < 4; ++i)
#pragma unroll
                for (int j = 0; j < 4; ++j) {
                    union { unsigned short h[4]; unsigned long long u; } p;
#pragma unroll
                    for (int r = 0; r < 4; ++r) p.h[r] = f2bf(acc[i][j][r]);
                    int h = (n0 - 2048) + wn + j * 16 + col;
                    int t0 = tb + wm + i * 16 + rq;
                    *(unsigned long long*)(C + (size_t)h * ldt + t0) = p.u;
                }
        }
    }
}

// ---------------------------------------------------------------------------
// Linv[b][j] = 1 / sum_rh partial[b][rh][j], rh from j>>6 (lower rows only).
// ---------------------------------------------------------------------------
__global__ __launch_bounds__(256) void colsum_inv(
    const float* __restrict__ par, float* __restrict__ Linv, int T)
{
    int b = blockIdx.y;
    int j = blockIdx.x * 256 + threadIdx.x;
    const float* p = par + (size_t)b * 32 * 2048;
    float s = 0.f;
    for (int rh = j >> 6; rh < 32; ++rh) s += p[(size_t)rh * 2048 + j];
    Linv[b * 2048 + j] = 1.0f / s;
}

// ---------------------------------------------------------------------------
// Vt[b][h][t] *= Linv[b][t]   (Vt [B,H,T] bf16, 8 elems/thread)
// ---------------------------------------------------------------------------
__global__ __launch_bounds__(256) void scale_v(
    unsigned short* __restrict__ Vt, const float* __restrict__ Linv)
{
    size_t idx = ((size_t)blockIdx.x * 256 + threadIdx.x) * 8;
    int b = (int)(idx >> 21);            // H*T = 2^21
    int tt = (int)(idx & 2047);
    bf16x8 v = *(bf16x8*)(Vt + idx);
    const float* L = Linv + b * 2048 + tt;
#pragma unroll
    for (int e = 0; e < 8; ++e)
        v[e] = (short)f2bf(bf2f((unsigned short)v[e]) * L[e]);
    *(bf16x8*)(Vt + idx) = v;
}

// ---------------------------------------------------------------------------
extern "C" void kernel_launch(void* const* d_in, const int* in_sizes, int n_in,
                              void* d_out, int out_size, void* d_ws, size_t ws_size,
                              hipStream_t stream)
{
    const int B = 4, T = 2048, E = 1024, H = 1024;
    const int M = B * T;                       // 8192
    const float* X  = (const float*)d_in[0];
    const float* Wq = (const float*)d_in[1];
    const float* Wk = (const float*)d_in[2];
    const float* Wv = (const float*)d_in[3];
    float* out = (float*)d_out;
    char* ws = (char*)d_ws;
    const size_t MB = 1024 * 1024;

    unsigned short* Xb  = (unsigned short*)(ws + 0);        // [ 0,16) MB
    unsigned short* WqT = (unsigned short*)(ws + 16 * MB);  // [16,18) contiguous with WkT,WvT
    unsigned short* WkT = (unsigned short*)(ws + 18 * MB);  // [18,20)
    unsigned short* WvT = (unsigned short*)(ws + 20 * MB);  // [20,22)
    unsigned short* Qb  = (unsigned short*)(ws + 32 * MB);  // [32,48)
    unsigned short* Kb  = (unsigned short*)(ws + 48 * MB);  // [48,64)
    unsigned short* Vt  = (unsigned short*)(ws + 64 * MB);  // [64,80) Vt [B,H,T]
    unsigned short* Eb  = (unsigned short*)(ws + 0);        // [ 0,32) overlays Xb/W (dead)
    float*          Linv = (float*)(ws + 32 * MB);          // 32 KB over dead Qb
    float*          par  = (float*)d_out;                   // 1 MB, dead until PV

    // 1. casts / weight transposes
    cast_kernel<<<dim3((M * E) / 1024), 256, 0, stream>>>(X, Xb, (size_t)M * E);
    transpose_cast_kernel<<<dim3(H / 64, E / 64), 256, 0, stream>>>(Wq, WqT, E, H);
    transpose_cast_kernel<<<dim3(H / 64, E / 64), 256, 0, stream>>>(Wk, WkT, E, H);
    transpose_cast_kernel<<<dim3(H / 64, E / 64), 256, 0, stream>>>(Wv, WvT, E, H);

    // 2. fused QKV: [8192,3072] vs concat W^T; Q,K row-major, V -> Vt [B,H,T]
    //    two 768-block dispatches (tm 0-31, 32-63): one occupancy round each,
    //    and each half (<32us) lets scores/PV surface in top-5 profiling.
    gemm_nt<4><<<dim3(24, 32, 1), 256, 0, stream>>>(
        Xb, WqT, Qb, Kb, Vt, nullptr, M, 3 * H, E, 0, 0, 0, 1.f, T);
    gemm_nt<4><<<dim3(24, 32, 1), 256, 0, stream>>>(
        Xb, WqT, Qb, Kb, Vt, nullptr, M, 3 * H, E, 0, 0, 32, 1.f, T);

    // 3. scores: E[i][j] = exp((Q K^T)[i][j]/32) masked, + column partials
    //    XCD-chunked triangular grid: 136 lower-triangle tiles per batch
    gemm_nt<5><<<dim3(136, 1, B), 256, 0, stream>>>(
        Qb, Kb, Eb, nullptr, nullptr, par, T, T, H,
        (size_t)T * H, (size_t)T * H, (size_t)T * T, 0.03125f, T);

    // 4. Linv = 1/colsum;  Vt *= Linv (folds softmax denominator into V)
    colsum_inv<<<dim3(T / 256, B), 256, 0, stream>>>(par, Linv, T);
    scale_v<<<dim3((B * H * T) / 2048), 256, 0, stream>>>(Vt, Linv);

    // 5. out = E (V/L)  (NT with scaled Vt), causal K-limit
    gemm_nt<2><<<dim3(H / 128, T / 128, B), 256, 0, stream>>>(
        Eb, Vt, out, nullptr, nullptr, nullptr, T, H, T,
        (size_t)T * T, (size_t)H * T, (size_t)T * H, 1.f, 0);
}

// Round 6
// 228.401 us; speedup vs baseline: 1.1016x; 1.0870x over previous
//
#include <hip/hip_runtime.h>
#include <hip/hip_bf16.h>
#include <stdint.h>

// ---------------------------------------------------------------------------
// MaskedAttention: out = colsoftmax(tril(Q K^T / sqrt(E))) @ V
// B=4, T=2048, E=H=1024.  Softmax over the QUERY axis (axis=1) per column j.
//
// R16 (R15 passed 248.3us; PV finally profiled: 43.9us, Mfma 14%, HBM 32%,
// Occupancy 9.4% -> latency/IMBALANCE-bound, not BW/compute.  Also the sum
// of all dispatch times ~170us < 248us wall -> ~75us of inter-dispatch gaps):
//  * PV: complement-paired 1D grid (512 blocks, 2/CU): slot pairs get
//    tm=(15-k) + tm=k -> every CU does ~17 K-steps (was up to 32 vs 2).
//    tn = id&7 keeps per-XCD Vt-band locality.  Mapping-only change.
//  * dispatch count 10 -> 5: {cast + 3 weight transposes} -> prep_kernel;
//    QKV re-merged into one 1536-block dispatch (R10 verified mapping);
//    {colsum_inv + scale_v} -> colsum_scale (Linv in LDS, scaled Vt write).
//
// Workspace 80 MB, liveness overlays:
//   [ 0,16) Xb      (dead after QKV)      -> E bf16 [0,32) at scores step
//   [16,22) WqT|WkT|WvT contiguous [3072,1024] (dead after QKV)
//   [32,48) Qb      (dead after scores)
//   [48,64) Kb      (dead after scores)
//   [64,80) Vt [B,H,T] (written by QKV epilogue, scaled in place, read by PV)
//   partial column sums [B,32,T] fp32 (1 MB) live in d_out (dead until PV).
// ---------------------------------------------------------------------------

typedef short bf16x8 __attribute__((ext_vector_type(8)));
typedef float f32x4  __attribute__((ext_vector_type(4)));

__device__ __forceinline__ unsigned short f2bf(float f) {
    union { float f; unsigned u; } x; x.f = f;
    unsigned r = x.u + 0x7FFFu + ((x.u >> 16) & 1u);
    return (unsigned short)(r >> 16);
}
__device__ __forceinline__ float bf2f(unsigned short h) {
    union { unsigned u; float f; } x; x.u = ((unsigned)h) << 16;
    return x.f;
}

// ---------------------------------------------------------------------------
// prep: blocks [0,8192) cast X fp32->bf16 (4 elems/thread);
//       blocks [8192,8960) transpose+cast Wq/Wk/Wv [1024,1024] -> WT.
// ---------------------------------------------------------------------------
__global__ __launch_bounds__(256) void prep_kernel(
    const float* __restrict__ X,
    const float* __restrict__ Wq, const float* __restrict__ Wk,
    const float* __restrict__ Wv,
    unsigned short* __restrict__ Xb, unsigned short* __restrict__ WT)
{
    __shared__ unsigned short tile[64][65];
    unsigned id = blockIdx.x;
    if (id < 8192) {
        size_t i = ((size_t)id * 256 + threadIdx.x) * 4;
        float4 v = *(const float4*)(X + i);
        union { unsigned short h[4]; unsigned long long u; } p;
        p.h[0] = f2bf(v.x); p.h[1] = f2bf(v.y);
        p.h[2] = f2bf(v.z); p.h[3] = f2bf(v.w);
        *(unsigned long long*)(Xb + i) = p.u;
    } else {
        unsigned w = id - 8192;
        unsigned which = w >> 8;                 // 0,1,2
        const float* W = (which == 0) ? Wq : (which == 1) ? Wk : Wv;
        unsigned short* out = WT + (size_t)which * 1024 * 1024;
        const int R = 1024, C = 1024;
        unsigned t2 = w & 255;
        int c0 = (int)(t2 & 15) * 64, r0 = (int)(t2 >> 4) * 64;
        int tx = threadIdx.x & 63, ty = threadIdx.x >> 6;
#pragma unroll
        for (int i = 0; i < 16; ++i) {
            int r = ty + i * 4;
            tile[r][tx] = f2bf(W[(size_t)(r0 + r) * C + c0 + tx]);
        }
        __syncthreads();
#pragma unroll
        for (int i = 0; i < 16; ++i) {
            int c = ty + i * 4;
            out[(size_t)(c0 + c) * R + r0 + tx] = tile[tx][c];
        }
    }
}

// ---------------------------------------------------------------------------
// NT bf16 GEMM: C[M,N] = A[M,K] * B[N,K]^T
// 128x128 tile, BK=64, 256 threads = 4 waves of 64x64, 16x16x32 bf16 MFMA,
// XOR-swizzled LDS, register-prefetch pipeline (named scalars).
// MODE 2: PV. C fp32, K limited to m0+128 (causal).  1D complement-paired
//         grid (512): tn=id&7 (XCD-banded Vt), slot pairs tm=(15-k)+k so
//         each CU's 2 resident blocks total ~17 K-steps.
// MODE 4: fused QKV; XCD-banded (8 tm-rows x 24 tn per XCD), 1536 blocks.
// MODE 5: scores: XCD-chunked triangular grid (136,1,B); E = exp(s*scale)
//         bf16 via LDS-coalesced store (masked on diagonal tile) + column
//         partials -> fpar[b][rh][j]
// ---------------------------------------------------------------------------
template <int MODE>
__global__ __launch_bounds__(256, 3) void gemm_nt(
    const unsigned short* __restrict__ A, const unsigned short* __restrict__ B,
    void* __restrict__ Cout, unsigned short* __restrict__ C2,
    unsigned short* __restrict__ C3, float* __restrict__ fpar,
    int M, int N, int K,
    size_t sAb, size_t sBb, size_t sCb, float scale, int ldt)
{
    int tn, tm, bz = blockIdx.z;
    if (MODE == 4) {
        // XCD-banded: xcd = id&7 owns tm in [xcd*8, xcd*8+8) x all 24 tn
        unsigned id = blockIdx.y * gridDim.x + blockIdx.x;
        unsigned xcd = id & 7, k2 = id >> 3;
        tm = (int)(xcd * 8 + (k2 & 7));
        tn = (int)(k2 >> 3);
    } else if (MODE == 5) {
        // XCD-chunked triangular: tile = (bx&7)*17 + bx>>3 (136 = 8x17)
        int bxr = blockIdx.x;
        int tid = (bxr & 7) * 17 + (bxr >> 3);
        tm = (int)((sqrtf(8.f * (float)tid + 1.f) - 1.f) * 0.5f);
        while ((tm + 1) * (tm + 2) / 2 <= tid) ++tm;
        while (tm * (tm + 1) / 2 > tid) --tm;
        tn = tid - tm * (tm + 1) / 2;
    } else {
        // MODE 2: complement-paired 1D decode
        unsigned n = blockIdx.x;           // [0,512)
        tn = (int)(n & 7u);
        unsigned q = n >> 3, half = q >> 5, r = q & 31u;
        bz = (int)((half ? 2u : 0u) + (r & 1u));
        tm = half ? (int)(r >> 1) : (int)(15u - (r >> 1));
    }
    A += (size_t)bz * sAb;
    B += (size_t)bz * sBb;
    int m0 = tm * 128, n0 = tn * 128;
    int kmax = (MODE == 2) ? (m0 + 128) : K;

    // contiguous 32 KB: A-tile at [0,16K), B-tile at [16K,32K); reused as a
    // 128x128 bf16 tile by the MODE-5 epilogue.
    __shared__ unsigned short sAB[2 * 128 * 64];
    char* sAc = (char*)sAB;
    char* sBc = (char*)sAB + 16384;

    unsigned t = threadIdx.x, lane = t & 63, wave = t >> 6;

    // staging: chunk ca = t + 256q, row = (ca&511)>>2, LDS byte ca*16.
    // Swizzle: global 16B group g = (ca&3) ^ ((row>>1)&3).
    unsigned srow = t >> 2;
    unsigned gsw = (t & 3) ^ ((t >> 3) & 3);
    const unsigned short* pA = A + (size_t)(m0 + srow) * K + gsw * 8;
    const unsigned short* pB = B + (size_t)(n0 + srow) * K + gsw * 8;
    const size_t rstep = (size_t)64 * K;
    unsigned ldsOff = t * 16;   // bytes; chunks q1/q2/q3 at +4096/+8192/+12288

    unsigned wm = (wave >> 1) * 64, wn = (wave & 1) * 64;
    unsigned lrow = lane & 15;
    // swizzled k-offset, lane-constant (row bits 1..2 == lrow bits 1..2)
    unsigned lk = ((lane >> 4) ^ ((lane >> 1) & 3)) * 8;
    const short* sAs = (const short*)sAB;
    const short* sBs = (const short*)(sAB + 128 * 64);

    f32x4 acc[4][4] = {};

    // prologue: prefetch tile 0 into named registers
    int4 rA0 = *(const int4*)(pA);
    int4 rA1 = *(const int4*)(pA + rstep);
    int4 rA2 = *(const int4*)(pA + 32);
    int4 rA3 = *(const int4*)(pA + rstep + 32);
    int4 rB0 = *(const int4*)(pB);
    int4 rB1 = *(const int4*)(pB + rstep);
    int4 rB2 = *(const int4*)(pB + 32);
    int4 rB3 = *(const int4*)(pB + rstep + 32);

    for (int k0 = 0; k0 < kmax; k0 += 64) {
        __syncthreads();                 // prev LDS reads done; vmcnt drained
        *(int4*)(sAc + ldsOff)         = rA0;
        *(int4*)(sAc + ldsOff + 4096)  = rA1;
        *(int4*)(sAc + ldsOff + 8192)  = rA2;
        *(int4*)(sAc + ldsOff + 12288) = rA3;
        *(int4*)(sBc + ldsOff)         = rB0;
        *(int4*)(sBc + ldsOff + 4096)  = rB1;
        *(int4*)(sBc + ldsOff + 8192)  = rB2;
        *(int4*)(sBc + ldsOff + 12288) = rB3;
        __syncthreads();                 // publish LDS tile

        if (k0 + 64 < kmax) {            // issue next tile; lands during MFMA
            pA += 64; pB += 64;
            rA0 = *(const int4*)(pA);
            rA1 = *(const int4*)(pA + rstep);
            rA2 = *(const int4*)(pA + 32);
            rA3 = *(const int4*)(pA + rstep + 32);
            rB0 = *(const int4*)(pB);
            rB1 = *(const int4*)(pB + rstep);
            rB2 = *(const int4*)(pB + 32);
            rB3 = *(const int4*)(pB + rstep + 32);
        }

#pragma unroll
        for (int kk = 0; kk < 2; ++kk) {
            bf16x8 a[4], b[4];
#pragma unroll
            for (int i = 0; i < 4; ++i) {
                a[i] = *(const bf16x8*)(sAs + kk * 4096 + (wm + i * 16 + lrow) * 32 + lk);
                b[i] = *(const bf16x8*)(sBs + kk * 4096 + (wn + i * 16 + lrow) * 32 + lk);
            }
#pragma unroll
            for (int i = 0; i < 4; ++i)
#pragma unroll
                for (int j = 0; j < 4; ++j)
                    acc[i][j] = __builtin_amdgcn_mfma_f32_16x16x32_bf16(
                        a[i], b[j], acc[i][j], 0, 0, 0);
        }
    }

    // epilogue: D col = lane&15, row = (lane>>4)*4 + reg
    unsigned col = lane & 15, rq = (lane >> 4) * 4;
    if (MODE == 2) {
        float* C = (float*)Cout + (size_t)bz * sCb;
#pragma unroll
        for (int i = 0; i < 4; ++i)
#pragma unroll
            for (int j = 0; j < 4; ++j)
#pragma unroll
                for (int r = 0; r < 4; ++r)
                    C[(size_t)(m0 + wm + i * 16 + rq + r) * N + n0 + wn + j * 16 + col] =
                        acc[i][j][r];
    } else if (MODE == 5) {   // scores -> E = exp, LDS-coalesced + col partials
        unsigned short* Ebp = (unsigned short*)Cout + (size_t)bz * sCb;
        float* par = fpar + (size_t)bz * 32 * 2048;
        bool diag = (tm == tn);
        unsigned short* tile = sAB;          // 128x128 bf16 = 32 KB
        __syncthreads();                     // all waves done reading A/B tiles
#pragma unroll
        for (int jj = 0; jj < 4; ++jj) {
            float csum = 0.f;
            int jl = (int)(wn + jj * 16 + col);
            int jg = n0 + jl;
#pragma unroll
            for (int ii = 0; ii < 4; ++ii) {
#pragma unroll
                for (int r = 0; r < 4; ++r) {
                    int il = (int)(wm + ii * 16 + rq + r);
                    int ig = m0 + il;
                    unsigned short us = 0;
                    if (!diag || ig >= jg)
                        us = f2bf(__expf(acc[ii][jj][r] * scale));
                    tile[il * 128 + jl] = us;
                    csum += bf2f(us);
                }
            }
            csum += __shfl_xor(csum, 16);
            csum += __shfl_xor(csum, 32);
            if (lane < 16) {
                int rh = (m0 + wm) >> 6;
                par[(size_t)rh * 2048 + n0 + wn + jj * 16 + lane] = csum;
            }
        }
        __syncthreads();                     // tile fully written
        // coalesced store: 8 passes x 256 threads x 16B (256B/16-lane group)
        {
            unsigned rr = t >> 4, cc = (t & 15) * 8;
#pragma unroll
            for (int p = 0; p < 8; ++p) {
                int li = (int)(p * 16 + rr);
                int4 v = *(const int4*)(tile + li * 128 + cc);
                *(int4*)(Ebp + (size_t)(m0 + li) * N + n0 + cc) = v;
            }
        }
    } else {                  // MODE 4: fused QKV
        if (n0 < 2048) {      // Q or K, row-major [8192,1024]
            unsigned short* C = (n0 < 1024) ? (unsigned short*)Cout : C2;
            int nb = n0 & 1023;
#pragma unroll
            for (int i = 0; i < 4; ++i)
#pragma unroll
                for (int j = 0; j < 4; ++j)
#pragma unroll
                    for (int r = 0; r < 4; ++r)
                        C[(size_t)(m0 + wm + i * 16 + rq + r) * 1024 + nb + wn + j * 16 + col] =
                            f2bf(acc[i][j][r]);
        } else {              // V transposed into Vt [B,H,T]
            int batch = m0 >> 11, tb = m0 & 2047;
            unsigned short* C = C3 + (size_t)batch * 1024 * 2048;
#pragma unroll
            for (int i = 0; i < 4; ++i)
#pragma unroll
                for (int j = 0; j < 4; ++j) {
                    union { unsigned short h[4]; unsigned long long u; } p;
#pragma unroll
                    for (int r = 0; r < 4; ++r) p.h[r] = f2bf(acc[i][j][r]);
                    int h = (n0 - 2048) + wn + j * 16 + col;
                    int t0 = tb + wm + i * 16 + rq;
                    *(unsigned long long*)(C + (size_t)h * ldt + t0) = p.u;
                }
        }
    }
}

// ---------------------------------------------------------------------------
// colsum_scale: Linv[j] = 1/sum_rh par[b][rh][j] (rh >= j>>6), then
// Vt[b][h][t0..t0+64) *= Linv.  Grid (T/64, B), 256 threads.
// ---------------------------------------------------------------------------
__global__ __launch_bounds__(256) void colsum_scale(
    const float* __restrict__ par, unsigned short* __restrict__ Vt)
{
    int b = blockIdx.y, t0 = blockIdx.x * 64;
    __shared__ float Ls[64];
    int tid = threadIdx.x;
    if (tid < 64) {
        int j = t0 + tid;
        const float* p = par + (size_t)b * 32 * 2048;
        float s = 0.f;
        for (int rh = j >> 6; rh < 32; ++rh) s += p[(size_t)rh * 2048 + j];
        Ls[tid] = 1.0f / s;
    }
    __syncthreads();
    unsigned short* V = Vt + ((size_t)b << 21);
    int c8 = (tid & 7) * 8;
#pragma unroll 4
    for (int hb = 0; hb < 1024; hb += 32) {
        int h = hb + (tid >> 3);
        size_t idx = (size_t)h * 2048 + t0 + c8;
        bf16x8 v = *(bf16x8*)(V + idx);
#pragma unroll
        for (int e = 0; e < 8; ++e)
            v[e] = (short)f2bf(bf2f((unsigned short)v[e]) * Ls[c8 + e]);
        *(bf16x8*)(V + idx) = v;
    }
}

// ---------------------------------------------------------------------------
extern "C" void kernel_launch(void* const* d_in, const int* in_sizes, int n_in,
                              void* d_out, int out_size, void* d_ws, size_t ws_size,
                              hipStream_t stream)
{
    const int B = 4, T = 2048, E = 1024, H = 1024;
    const int M = B * T;                       // 8192
    const float* X  = (const float*)d_in[0];
    const float* Wq = (const float*)d_in[1];
    const float* Wk = (const float*)d_in[2];
    const float* Wv = (const float*)d_in[3];
    float* out = (float*)d_out;
    char* ws = (char*)d_ws;
    const size_t MB = 1024 * 1024;

    unsigned short* Xb  = (unsigned short*)(ws + 0);        // [ 0,16) MB
    unsigned short* WqT = (unsigned short*)(ws + 16 * MB);  // [16,22) contiguous q|k|v
    unsigned short* Qb  = (unsigned short*)(ws + 32 * MB);  // [32,48)
    unsigned short* Kb  = (unsigned short*)(ws + 48 * MB);  // [48,64)
    unsigned short* Vt  = (unsigned short*)(ws + 64 * MB);  // [64,80) Vt [B,H,T]
    unsigned short* Eb  = (unsigned short*)(ws + 0);        // [ 0,32) overlays Xb/W (dead)
    float*          par  = (float*)d_out;                   // 1 MB, dead until PV

    // 1. fused prep: cast X (8192 blocks) + 3 weight transposes (768 blocks)
    prep_kernel<<<dim3(8960), 256, 0, stream>>>(X, Wq, Wk, Wv, Xb, WqT);

    // 2. fused QKV: [8192,3072] vs concat W^T; Q,K row-major, V -> Vt [B,H,T]
    gemm_nt<4><<<dim3(24, 64, 1), 256, 0, stream>>>(
        Xb, WqT, Qb, Kb, Vt, nullptr, M, 3 * H, E, 0, 0, 0, 1.f, T);

    // 3. scores: E[i][j] = exp((Q K^T)[i][j]/32) masked, + column partials
    //    XCD-chunked triangular grid: 136 lower-triangle tiles per batch
    gemm_nt<5><<<dim3(136, 1, B), 256, 0, stream>>>(
        Qb, Kb, Eb, nullptr, nullptr, par, T, T, H,
        (size_t)T * H, (size_t)T * H, (size_t)T * T, 0.03125f, T);

    // 4. Linv = 1/colsum fused with Vt *= Linv
    colsum_scale<<<dim3(T / 64, B), 256, 0, stream>>>(par, Vt);

    // 5. out = E (V/L)  (NT with scaled Vt), causal K-limit,
    //    complement-paired 1D grid (512 blocks)
    gemm_nt<2><<<dim3(512, 1, 1), 256, 0, stream>>>(
        Eb, Vt, out, nullptr, nullptr, nullptr, T, H, T,
        (size_t)T * T, (size_t)H * T, (size_t)T * H, 1.f, 0);
}

// Round 7
// 224.416 us; speedup vs baseline: 1.1212x; 1.0178x over previous
//
#include <hip/hip_runtime.h>
#include <hip/hip_bf16.h>
#include <stdint.h>

// ---------------------------------------------------------------------------
// MaskedAttention: out = colsoftmax(tril(Q K^T / sqrt(E))) @ V
// B=4, T=2048, E=H=1024.  Softmax over the QUERY axis (axis=1) per column j.
//
// R17 (R16 passed 228.4us, -19.9):
//  * scores -> scores64 kernel: 128x64 tiles, 1088 blocks (4.25/CU at
//    launch_bounds(256,4), LDS 24KB).  The 2-barrier GEMM structure needs
//    >=3 blocks/CU to hide its staging drain (m114); the old 544-block
//    scores ran at 2.1/CU.  Uniform 16 K-steps/block; XCD-chunked
//    triangular decode (272 = 8x34 per batch).
//  * colsum_scale: grid 128 -> 1024 blocks (32 t-bands x 8 h-bands x 4
//    batches); Linv recomputed per h-band (par is 1MB, L2-hot); scaling
//    pass fully coalesced.  R16's 128-block version left half the CUs idle.
//  * QKV / PV / prep untouched (verified paths).
//
// Workspace 80 MB, liveness overlays:
//   [ 0,16) Xb      (dead after QKV)      -> E bf16 [0,32) at scores step
//   [16,22) WqT|WkT|WvT contiguous [3072,1024] (dead after QKV)
//   [32,48) Qb      (dead after scores)
//   [48,64) Kb      (dead after scores)
//   [64,80) Vt [B,H,T] (written by QKV epilogue, scaled in place, read by PV)
//   partial column sums [B,32,T] fp32 (1 MB) live in d_out (dead until PV).
// ---------------------------------------------------------------------------

typedef short bf16x8 __attribute__((ext_vector_type(8)));
typedef float f32x4  __attribute__((ext_vector_type(4)));

__device__ __forceinline__ unsigned short f2bf(float f) {
    union { float f; unsigned u; } x; x.f = f;
    unsigned r = x.u + 0x7FFFu + ((x.u >> 16) & 1u);
    return (unsigned short)(r >> 16);
}
__device__ __forceinline__ float bf2f(unsigned short h) {
    union { unsigned u; float f; } x; x.u = ((unsigned)h) << 16;
    return x.f;
}

// ---------------------------------------------------------------------------
// prep: blocks [0,8192) cast X fp32->bf16 (4 elems/thread);
//       blocks [8192,8960) transpose+cast Wq/Wk/Wv [1024,1024] -> WT.
// ---------------------------------------------------------------------------
__global__ __launch_bounds__(256) void prep_kernel(
    const float* __restrict__ X,
    const float* __restrict__ Wq, const float* __restrict__ Wk,
    const float* __restrict__ Wv,
    unsigned short* __restrict__ Xb, unsigned short* __restrict__ WT)
{
    __shared__ unsigned short tile[64][65];
    unsigned id = blockIdx.x;
    if (id < 8192) {
        size_t i = ((size_t)id * 256 + threadIdx.x) * 4;
        float4 v = *(const float4*)(X + i);
        union { unsigned short h[4]; unsigned long long u; } p;
        p.h[0] = f2bf(v.x); p.h[1] = f2bf(v.y);
        p.h[2] = f2bf(v.z); p.h[3] = f2bf(v.w);
        *(unsigned long long*)(Xb + i) = p.u;
    } else {
        unsigned w = id - 8192;
        unsigned which = w >> 8;                 // 0,1,2
        const float* W = (which == 0) ? Wq : (which == 1) ? Wk : Wv;
        unsigned short* out = WT + (size_t)which * 1024 * 1024;
        const int R = 1024, C = 1024;
        unsigned t2 = w & 255;
        int c0 = (int)(t2 & 15) * 64, r0 = (int)(t2 >> 4) * 64;
        int tx = threadIdx.x & 63, ty = threadIdx.x >> 6;
#pragma unroll
        for (int i = 0; i < 16; ++i) {
            int r = ty + i * 4;
            tile[r][tx] = f2bf(W[(size_t)(r0 + r) * C + c0 + tx]);
        }
        __syncthreads();
#pragma unroll
        for (int i = 0; i < 16; ++i) {
            int c = ty + i * 4;
            out[(size_t)(c0 + c) * R + r0 + tx] = tile[tx][c];
        }
    }
}

// ---------------------------------------------------------------------------
// NT bf16 GEMM: C[M,N] = A[M,K] * B[N,K]^T
// 128x128 tile, BK=64, 256 threads = 4 waves of 64x64, 16x16x32 bf16 MFMA,
// XOR-swizzled LDS, register-prefetch pipeline (named scalars).
// MODE 2: PV. C fp32, K limited to m0+128 (causal).  1D complement-paired
//         grid (512): tn=id&7 (XCD-banded Vt), slot pairs tm=(15-k)+k so
//         each CU's 2 resident blocks total ~17 K-steps.
// MODE 4: fused QKV; XCD-banded (8 tm-rows x 24 tn per XCD), 1536 blocks.
// ---------------------------------------------------------------------------
template <int MODE>
__global__ __launch_bounds__(256, 3) void gemm_nt(
    const unsigned short* __restrict__ A, const unsigned short* __restrict__ B,
    void* __restrict__ Cout, unsigned short* __restrict__ C2,
    unsigned short* __restrict__ C3, float* __restrict__ fpar,
    int M, int N, int K,
    size_t sAb, size_t sBb, size_t sCb, float scale, int ldt)
{
    int tn, tm, bz = blockIdx.z;
    if (MODE == 4) {
        // XCD-banded: xcd = id&7 owns tm in [xcd*8, xcd*8+8) x all 24 tn
        unsigned id = blockIdx.y * gridDim.x + blockIdx.x;
        unsigned xcd = id & 7, k2 = id >> 3;
        tm = (int)(xcd * 8 + (k2 & 7));
        tn = (int)(k2 >> 3);
    } else {
        // MODE 2: complement-paired 1D decode
        unsigned n = blockIdx.x;           // [0,512)
        tn = (int)(n & 7u);
        unsigned q = n >> 3, half = q >> 5, r = q & 31u;
        bz = (int)((half ? 2u : 0u) + (r & 1u));
        tm = half ? (int)(r >> 1) : (int)(15u - (r >> 1));
    }
    A += (size_t)bz * sAb;
    B += (size_t)bz * sBb;
    int m0 = tm * 128, n0 = tn * 128;
    int kmax = (MODE == 2) ? (m0 + 128) : K;

    __shared__ unsigned short sAB[2 * 128 * 64];
    char* sAc = (char*)sAB;
    char* sBc = (char*)sAB + 16384;

    unsigned t = threadIdx.x, lane = t & 63, wave = t >> 6;

    // staging: chunk ca = t + 256q, row = (ca&511)>>2, LDS byte ca*16.
    // Swizzle: global 16B group g = (ca&3) ^ ((row>>1)&3).
    unsigned srow = t >> 2;
    unsigned gsw = (t & 3) ^ ((t >> 3) & 3);
    const unsigned short* pA = A + (size_t)(m0 + srow) * K + gsw * 8;
    const unsigned short* pB = B + (size_t)(n0 + srow) * K + gsw * 8;
    const size_t rstep = (size_t)64 * K;
    unsigned ldsOff = t * 16;   // bytes; chunks q1/q2/q3 at +4096/+8192/+12288

    unsigned wm = (wave >> 1) * 64, wn = (wave & 1) * 64;
    unsigned lrow = lane & 15;
    unsigned lk = ((lane >> 4) ^ ((lane >> 1) & 3)) * 8;
    const short* sAs = (const short*)sAB;
    const short* sBs = (const short*)(sAB + 128 * 64);

    f32x4 acc[4][4] = {};

    int4 rA0 = *(const int4*)(pA);
    int4 rA1 = *(const int4*)(pA + rstep);
    int4 rA2 = *(const int4*)(pA + 32);
    int4 rA3 = *(const int4*)(pA + rstep + 32);
    int4 rB0 = *(const int4*)(pB);
    int4 rB1 = *(const int4*)(pB + rstep);
    int4 rB2 = *(const int4*)(pB + 32);
    int4 rB3 = *(const int4*)(pB + rstep + 32);

    for (int k0 = 0; k0 < kmax; k0 += 64) {
        __syncthreads();
        *(int4*)(sAc + ldsOff)         = rA0;
        *(int4*)(sAc + ldsOff + 4096)  = rA1;
        *(int4*)(sAc + ldsOff + 8192)  = rA2;
        *(int4*)(sAc + ldsOff + 12288) = rA3;
        *(int4*)(sBc + ldsOff)         = rB0;
        *(int4*)(sBc + ldsOff + 4096)  = rB1;
        *(int4*)(sBc + ldsOff + 8192)  = rB2;
        *(int4*)(sBc + ldsOff + 12288) = rB3;
        __syncthreads();

        if (k0 + 64 < kmax) {
            pA += 64; pB += 64;
            rA0 = *(const int4*)(pA);
            rA1 = *(const int4*)(pA + rstep);
            rA2 = *(const int4*)(pA + 32);
            rA3 = *(const int4*)(pA + rstep + 32);
            rB0 = *(const int4*)(pB);
            rB1 = *(const int4*)(pB + rstep);
            rB2 = *(const int4*)(pB + 32);
            rB3 = *(const int4*)(pB + rstep + 32);
        }

#pragma unroll
        for (int kk = 0; kk < 2; ++kk) {
            bf16x8 a[4], b[4];
#pragma unroll
            for (int i = 0; i < 4; ++i) {
                a[i] = *(const bf16x8*)(sAs + kk * 4096 + (wm + i * 16 + lrow) * 32 + lk);
                b[i] = *(const bf16x8*)(sBs + kk * 4096 + (wn + i * 16 + lrow) * 32 + lk);
            }
#pragma unroll
            for (int i = 0; i < 4; ++i)
#pragma unroll
                for (int j = 0; j < 4; ++j)
                    acc[i][j] = __builtin_amdgcn_mfma_f32_16x16x32_bf16(
                        a[i], b[j], acc[i][j], 0, 0, 0);
        }
    }

    unsigned col = lane & 15, rq = (lane >> 4) * 4;
    if (MODE == 2) {
        float* C = (float*)Cout + (size_t)bz * sCb;
#pragma unroll
        for (int i = 0; i < 4; ++i)
#pragma unroll
            for (int j = 0; j < 4; ++j)
#pragma unroll
                for (int r = 0; r < 4; ++r)
                    C[(size_t)(m0 + wm + i * 16 + rq + r) * N + n0 + wn + j * 16 + col] =
                        acc[i][j][r];
    } else {                  // MODE 4: fused QKV
        if (n0 < 2048) {      // Q or K, row-major [8192,1024]
            unsigned short* C = (n0 < 1024) ? (unsigned short*)Cout : C2;
            int nb = n0 & 1023;
#pragma unroll
            for (int i = 0; i < 4; ++i)
#pragma unroll
                for (int j = 0; j < 4; ++j)
#pragma unroll
                    for (int r = 0; r < 4; ++r)
                        C[(size_t)(m0 + wm + i * 16 + rq + r) * 1024 + nb + wn + j * 16 + col] =
                            f2bf(acc[i][j][r]);
        } else {              // V transposed into Vt [B,H,T]
            int batch = m0 >> 11, tb = m0 & 2047;
            unsigned short* C = C3 + (size_t)batch * 1024 * 2048;
#pragma unroll
            for (int i = 0; i < 4; ++i)
#pragma unroll
                for (int j = 0; j < 4; ++j) {
                    union { unsigned short h[4]; unsigned long long u; } p;
#pragma unroll
                    for (int r = 0; r < 4; ++r) p.h[r] = f2bf(acc[i][j][r]);
                    int h = (n0 - 2048) + wn + j * 16 + col;
                    int t0 = tb + wm + i * 16 + rq;
                    *(unsigned long long*)(C + (size_t)h * ldt + t0) = p.u;
                }
        }
    }
}

// ---------------------------------------------------------------------------
// scores64: E = exp(scale * Q K^T) masked causal, 128x64 tiles, + column
// partials par[b][rh][j].  Grid (272,1,B): xcd-chunked triangular decode
// (272 = 8x34; u = (bx&7)*34 + bx>>3; tm(tm+1) <= u < (tm+1)(tm+2)).
// 4 waves of 64x32 out; A-tile 16KB (2 row-halves x 2 k-halves), B-tile
// 8KB (2 k-halves); LDS 24KB -> 4 blocks/CU with launch_bounds(256,4).
// ---------------------------------------------------------------------------
__global__ __launch_bounds__(256, 4) void scores64_kernel(
    const unsigned short* __restrict__ A, const unsigned short* __restrict__ B,
    unsigned short* __restrict__ Eb, float* __restrict__ fpar, float scale)
{
    int bz = blockIdx.z;
    unsigned bx = blockIdx.x;                    // [0,272)
    int u = (int)((bx & 7u) * 34u + (bx >> 3));
    int tm = (int)((sqrtf(4.f * (float)u + 1.f) - 1.f) * 0.5f);
    while ((tm + 1) * (tm + 2) <= u) ++tm;
    while (tm * (tm + 1) > u) --tm;
    int tn64 = u - tm * (tm + 1);                // [0, 2tm+2)
    const int K = 1024;
    int m0 = tm * 128, n0 = tn64 * 64;
    A += (size_t)bz * (size_t)2048 * 1024;       // Qb batch panel
    B += (size_t)bz * (size_t)2048 * 1024;       // Kb batch panel

    // LDS 24KB: A [2 khalf][128 rows][64B] at 0..16383,
    //           B [2 khalf][ 64 rows][64B] at 16384..24575.
    __shared__ unsigned short sAB[12288];
    char* sAc = (char*)sAB;
    char* sBc = (char*)sAB + 16384;

    unsigned t = threadIdx.x, lane = t & 63, wave = t >> 6;
    unsigned srow = t >> 2;                      // [0,64)
    unsigned gsw = (t & 3) ^ ((t >> 3) & 3);     // key = (row>>1)&3
    const unsigned short* pA = A + (size_t)(m0 + srow) * K + gsw * 8;
    const unsigned short* pB = B + (size_t)(n0 + srow) * K + gsw * 8;
    const size_t rstep = (size_t)64 * K;
    unsigned ldsOff = t * 16;

    unsigned wm = (wave >> 1) * 64, wn = (wave & 1) * 32;
    unsigned lrow = lane & 15;
    unsigned lk = ((lane >> 4) ^ ((lane >> 1) & 3)) * 8;
    const short* sAs = (const short*)sAB;
    const short* sBs = (const short*)(sAB + 8192);   // byte 16384

    f32x4 acc[4][2] = {};

    int4 rA0 = *(const int4*)(pA);
    int4 rA1 = *(const int4*)(pA + rstep);
    int4 rA2 = *(const int4*)(pA + 32);
    int4 rA3 = *(const int4*)(pA + rstep + 32);
    int4 rB0 = *(const int4*)(pB);
    int4 rB1 = *(const int4*)(pB + 32);

    for (int k0 = 0; k0 < K; k0 += 64) {
        __syncthreads();
        *(int4*)(sAc + ldsOff)         = rA0;
        *(int4*)(sAc + ldsOff + 4096)  = rA1;
        *(int4*)(sAc + ldsOff + 8192)  = rA2;
        *(int4*)(sAc + ldsOff + 12288) = rA3;
        *(int4*)(sBc + ldsOff)         = rB0;
        *(int4*)(sBc + ldsOff + 4096)  = rB1;
        __syncthreads();

        if (k0 + 64 < K) {
            pA += 64; pB += 64;
            rA0 = *(const int4*)(pA);
            rA1 = *(const int4*)(pA + rstep);
            rA2 = *(const int4*)(pA + 32);
            rA3 = *(const int4*)(pA + rstep + 32);
            rB0 = *(const int4*)(pB);
            rB1 = *(const int4*)(pB + 32);
        }

#pragma unroll
        for (int kk = 0; kk < 2; ++kk) {
            bf16x8 a[4], b[2];
#pragma unroll
            for (int i = 0; i < 4; ++i)
                a[i] = *(const bf16x8*)(sAs + kk * 4096 + (wm + i * 16 + lrow) * 32 + lk);
#pragma unroll
            for (int j = 0; j < 2; ++j)
                b[j] = *(const bf16x8*)(sBs + kk * 2048 + (wn + j * 16 + lrow) * 32 + lk);
#pragma unroll
            for (int i = 0; i < 4; ++i)
#pragma unroll
                for (int j = 0; j < 2; ++j)
                    acc[i][j] = __builtin_amdgcn_mfma_f32_16x16x32_bf16(
                        a[i], b[j], acc[i][j], 0, 0, 0);
        }
    }

    // epilogue: exp + mask -> LDS tile [128][64] + column partials
    unsigned col = lane & 15, rq = (lane >> 4) * 4;
    unsigned short* Ebp = Eb + (size_t)bz * (size_t)2048 * 2048;
    float* par = fpar + (size_t)bz * 32 * 2048;
    bool diag = ((tn64 >> 1) == tm);
    unsigned short* tile = sAB;                  // [128][64] bf16 = 16KB
    __syncthreads();                             // A/B LDS reads complete
#pragma unroll
    for (int jj = 0; jj < 2; ++jj) {
        float csum = 0.f;
        int jl = (int)(wn + jj * 16 + col);
        int jg = n0 + jl;
#pragma unroll
        for (int ii = 0; ii < 4; ++ii) {
#pragma unroll
            for (int r = 0; r < 4; ++r) {
                int il = (int)(wm + ii * 16 + rq + r);
                int ig = m0 + il;
                unsigned short us = 0;
                if (!diag || ig >= jg)
                    us = f2bf(__expf(acc[ii][jj][r] * scale));
                tile[il * 64 + jl] = us;
                csum += bf2f(us);
            }
        }
        csum += __shfl_xor(csum, 16);
        csum += __shfl_xor(csum, 32);
        if (lane < 16) {
            int rh = (m0 + (int)wm) >> 6;
            par[(size_t)rh * 2048 + n0 + wn + jj * 16 + lane] = csum;
        }
    }
    __syncthreads();                             // tile fully written
    // coalesced store: 4 passes x 256 threads x 16B (128B bursts per row)
    {
        unsigned rr = t >> 3, cc = (t & 7) * 8;
#pragma unroll
        for (int p = 0; p < 4; ++p) {
            int li = (int)(p * 32 + rr);
            int4 v = *(const int4*)(tile + li * 64 + cc);
            *(int4*)(Ebp + (size_t)(m0 + li) * 2048 + n0 + cc) = v;
        }
    }
}

// ---------------------------------------------------------------------------
// colsum_scale: Linv[j] = 1/sum_rh par[b][rh][j] (rh >= j>>6), then
// Vt[b][h0..h0+128)[t0..t0+64) *= Linv.  Grid (32, 8, 4) = 1024 blocks;
// Linv recomputed per h-band (par is 1 MB, L2-hot -- redundancy is free).
// ---------------------------------------------------------------------------
__global__ __launch_bounds__(256) void colsum_scale(
    const float* __restrict__ par, unsigned short* __restrict__ Vt)
{
    int b = blockIdx.z, t0 = blockIdx.x * 64, h0 = blockIdx.y * 128;
    __shared__ float Ls[64];
    int tid = threadIdx.x;
    if (tid < 64) {
        int j = t0 + tid;
        const float* p = par + (size_t)b * 32 * 2048;
        float s = 0.f;
        for (int rh = j >> 6; rh < 32; ++rh) s += p[(size_t)rh * 2048 + j];
        Ls[tid] = 1.0f / s;
    }
    __syncthreads();
    unsigned short* V = Vt + ((size_t)b << 21);
    int c8 = (tid & 7) * 8;
#pragma unroll
    for (int rr = 0; rr < 4; ++rr) {
        int h = h0 + rr * 32 + (tid >> 3);
        size_t idx = (size_t)h * 2048 + t0 + c8;
        bf16x8 v = *(bf16x8*)(V + idx);
#pragma unroll
        for (int e = 0; e < 8; ++e)
            v[e] = (short)f2bf(bf2f((unsigned short)v[e]) * Ls[c8 + e]);
        *(bf16x8*)(V + idx) = v;
    }
}

// ---------------------------------------------------------------------------
extern "C" void kernel_launch(void* const* d_in, const int* in_sizes, int n_in,
                              void* d_out, int out_size, void* d_ws, size_t ws_size,
                              hipStream_t stream)
{
    const int B = 4, T = 2048, E = 1024, H = 1024;
    const int M = B * T;                       // 8192
    const float* X  = (const float*)d_in[0];
    const float* Wq = (const float*)d_in[1];
    const float* Wk = (const float*)d_in[2];
    const float* Wv = (const float*)d_in[3];
    float* out = (float*)d_out;
    char* ws = (char*)d_ws;
    const size_t MB = 1024 * 1024;

    unsigned short* Xb  = (unsigned short*)(ws + 0);        // [ 0,16) MB
    unsigned short* WqT = (unsigned short*)(ws + 16 * MB);  // [16,22) contiguous q|k|v
    unsigned short* Qb  = (unsigned short*)(ws + 32 * MB);  // [32,48)
    unsigned short* Kb  = (unsigned short*)(ws + 48 * MB);  // [48,64)
    unsigned short* Vt  = (unsigned short*)(ws + 64 * MB);  // [64,80) Vt [B,H,T]
    unsigned short* Eb  = (unsigned short*)(ws + 0);        // [ 0,32) overlays Xb/W (dead)
    float*          par  = (float*)d_out;                   // 1 MB, dead until PV

    // 1. fused prep: cast X (8192 blocks) + 3 weight transposes (768 blocks)
    prep_kernel<<<dim3(8960), 256, 0, stream>>>(X, Wq, Wk, Wv, Xb, WqT);

    // 2. fused QKV: [8192,3072] vs concat W^T; Q,K row-major, V -> Vt [B,H,T]
    gemm_nt<4><<<dim3(24, 64, 1), 256, 0, stream>>>(
        Xb, WqT, Qb, Kb, Vt, nullptr, M, 3 * H, E, 0, 0, 0, 1.f, T);

    // 3. scores64: E[i][j] = exp((Q K^T)[i][j]/32) masked, + column partials
    //    128x64 tiles, 4/CU occupancy, XCD-chunked triangular grid
    scores64_kernel<<<dim3(272, 1, B), 256, 0, stream>>>(
        Qb, Kb, Eb, par, 0.03125f);

    // 4. Linv = 1/colsum fused with Vt *= Linv (1024 blocks, full machine)
    colsum_scale<<<dim3(32, 8, 4), 256, 0, stream>>>(par, Vt);

    // 5. out = E (V/L)  (NT with scaled Vt), causal K-limit,
    //    complement-paired 1D grid (512 blocks)
    gemm_nt<2><<<dim3(512, 1, 1), 256, 0, stream>>>(
        Eb, Vt, out, nullptr, nullptr, nullptr, T, H, T,
        (size_t)T * T, (size_t)H * T, (size_t)T * H, 1.f, 0);
}